// Round 2
// baseline (261.200 us; speedup 1.0000x reference)
//
#include <hip/hip_runtime.h>
#include <math.h>

#define NEVENTS 16384
#define LHIST   2048
#define NCOMP   20
#define WAVES_PER_BLOCK 4

// One 64-lane wave per event row.
// Phase 1: 16 samples at stride 128 locate the 128-elem chunk.
// Phase 2: chunk read as float2 (512B coalesced); ballots give exact count.
__global__ __launch_bounds__(64 * WAVES_PER_BLOCK) void markov_kernel(
        const int*   __restrict__ src,
        const int*   __restrict__ dst,
        const float* __restrict__ t,
        const float* __restrict__ x_pad,
        const float* __restrict__ t_pad,
        const float* __restrict__ emb_src,
        const float* __restrict__ emb_dst,
        const float* __restrict__ alpha_p,
        const float* __restrict__ beta_p,
        float*       __restrict__ out) {
    const int wid  = blockIdx.x * WAVES_PER_BLOCK + (threadIdx.x >> 6);
    const int lane = threadIdx.x & 63;
    if (wid >= NEVENTS) return;
    const int e = wid;

    const float tq = t[e];
    const float* row = t_pad + (size_t)e * LHIST;

    // ---- phase 1: coarse search. lanes 0..15 sample row[128*i] ----
    const int spos = (lane < 16) ? (lane << 7) : 0;
    const float sv = row[spos];
    const unsigned long long b1 = __ballot(sv < tq) & 0xFFFFull;
    const int j = __popcll(b1) - 1;   // last chunk whose first elem < tq; -1 if none

    float incr = 0.0f;
    if (j >= 0) {
        // ---- phase 2: exact count within chunk j (128 elems, float2/lane) ----
        const float2* c2 = (const float2*)(row + ((size_t)j << 7));
        const float2 v = c2[lane];
        const int cin = __popcll(__ballot(v.x < tq)) + __popcll(__ballot(v.y < tq));
        // all elements before chunk j are < tq (sorted), so:
        // count = 128*j + cin  (cin >= 1), idx = count - 1
        const int li  = cin - 1;                   // local index within chunk
        const int idx = (j << 7) + li;

        const float cand = (li & 1) ? v.y : v.x;   // li is wave-uniform
        const float tl   = __shfl(cand, li >> 1);

        const float xv = x_pad[(size_t)e * LHIST + idx];  // uniform addr -> broadcast
        const float z  = (xv - 0.5f) * 4.0f;              // (x-MEAN)/VAR
        const float xs = 1.0f / (1.0f + __expf(-z));
        const float alpha = alpha_p[0];
        const float beta  = beta_p[0];
        incr = alpha * xs * __expf(-beta * (tq - tl));
    }

    // ---- base rate: softplus(<emb_src[src], emb_dst[dst]>), wave-parallel ----
    const int s = src[e];
    const int d = dst[e];
    float p = 0.0f;
    if (lane < NCOMP) {
        p = emb_src[(size_t)s * NCOMP + lane] * emb_dst[(size_t)d * NCOMP + lane];
    }
    #pragma unroll
    for (int off = 32; off > 0; off >>= 1) p += __shfl_xor(p, off);
    // stable softplus
    const float sp = fmaxf(p, 0.0f) + log1pf(expf(-fabsf(p)));

    if (lane == 0) out[e] = sp + incr;
}

extern "C" void kernel_launch(void* const* d_in, const int* in_sizes, int n_in,
                              void* d_out, int out_size, void* d_ws, size_t ws_size,
                              hipStream_t stream) {
    const int*   src     = (const int*)  d_in[0];
    const int*   dst     = (const int*)  d_in[1];
    const float* t       = (const float*)d_in[2];
    const float* x_pad   = (const float*)d_in[3];
    const float* t_pad   = (const float*)d_in[4];
    const float* emb_src = (const float*)d_in[5];
    const float* emb_dst = (const float*)d_in[6];
    const float* alpha_p = (const float*)d_in[7];
    const float* beta_p  = (const float*)d_in[8];
    float* out = (float*)d_out;

    const int blocks = NEVENTS / WAVES_PER_BLOCK;   // 4096 blocks x 256 threads
    markov_kernel<<<blocks, 64 * WAVES_PER_BLOCK, 0, stream>>>(
        src, dst, t, x_pad, t_pad, emb_src, emb_dst, alpha_p, beta_p, out);
}

// Round 3
// 235.455 us; speedup vs baseline: 1.1093x; 1.1093x over previous
//
#include <hip/hip_runtime.h>
#include <math.h>

#define NEVENTS 16384
#define LHIST   2048
#define NCOMP   20
#define WAVES_PER_BLOCK 4

// One 64-lane wave per event row.
// Main path: predicted 128-elem window (t_pad ~ sorted U[0,100] => count ~ Bin(L, t/100),
// std <= 22.6; +-64 window covers ~2.8 sigma). One coalesced 512B read + 2 ballots.
// Fallback (~0.5% of rows, wave-uniform branch): 2-phase hierarchical search.
__global__ __launch_bounds__(64 * WAVES_PER_BLOCK) void markov_kernel(
        const int*   __restrict__ src,
        const int*   __restrict__ dst,
        const float* __restrict__ t,
        const float* __restrict__ x_pad,
        const float* __restrict__ t_pad,
        const float* __restrict__ emb_src,
        const float* __restrict__ emb_dst,
        const float* __restrict__ alpha_p,
        const float* __restrict__ beta_p,
        float*       __restrict__ out) {
    const int wid  = blockIdx.x * WAVES_PER_BLOCK + (threadIdx.x >> 6);
    const int lane = threadIdx.x & 63;
    const int e = wid;

    const float tq = t[e];
    const float* row = t_pad + (size_t)e * LHIST;

    // ---- predicted window [w0, w0+128) ----
    int pred = (int)(tq * (LHIST / 100.0f));
    int w0 = pred - 64;
    w0 = (w0 < 0) ? 0 : ((w0 > LHIST - 128) ? (LHIST - 128) : w0);
    w0 &= ~1;                                   // float2 alignment
    const float2 v = ((const float2*)(row + w0))[lane];
    const int cin = __popcll(__ballot(v.x < tq)) + __popcll(__ballot(v.y < tq));

    int  count;
    float tl = 0.0f;
    bool have = false;

    if (cin > 0 && (cin < 128 || w0 + 128 == LHIST)) {
        // boundary inside window (or window ends at row end): count = w0 + cin
        count = w0 + cin;
        const int li = cin - 1;                 // wave-uniform
        const float cand = (li & 1) ? v.y : v.x;
        tl = __shfl(cand, li >> 1);
        have = true;
    } else if (cin == 0 && w0 == 0) {
        have = false;                           // no prev event at all
        count = 0;
    } else {
        // ---- fallback: 2-phase hierarchical search (rare, wave-uniform) ----
        const int spos = (lane < 16) ? (lane << 7) : 0;
        const float sv = row[spos];
        const unsigned long long b1 = __ballot(sv < tq) & 0xFFFFull;
        const int j = __popcll(b1) - 1;
        if (j >= 0) {
            const float2* c2 = (const float2*)(row + ((size_t)j << 7));
            const float2 w = c2[lane];
            const int c2in = __popcll(__ballot(w.x < tq)) + __popcll(__ballot(w.y < tq));
            count = (j << 7) + c2in;            // c2in >= 1 since row[j*128] < tq
            const int li = c2in - 1;
            const float cand = (li & 1) ? w.y : w.x;
            tl = __shfl(cand, li >> 1);
            have = true;
        } else {
            have = false;
            count = 0;
        }
    }

    float incr = 0.0f;
    if (have) {
        const int idx = count - 1;
        const float xv = x_pad[(size_t)e * LHIST + idx];  // uniform addr -> broadcast
        const float z  = (xv - 0.5f) * 4.0f;              // (x - MEAN)/VAR
        const float xs = 1.0f / (1.0f + __expf(-z));
        incr = alpha_p[0] * xs * __expf(-beta_p[0] * (tq - tl));
    }

    // ---- base rate: softplus(<emb_src[src], emb_dst[dst]>), wave-parallel ----
    const int s = src[e];
    const int d = dst[e];
    float p = 0.0f;
    if (lane < NCOMP) {
        p = emb_src[(size_t)s * NCOMP + lane] * emb_dst[(size_t)d * NCOMP + lane];
    }
    #pragma unroll
    for (int off = 32; off > 0; off >>= 1) p += __shfl_xor(p, off);
    const float sp = fmaxf(p, 0.0f) + log1pf(expf(-fabsf(p)));

    if (lane == 0) out[e] = sp + incr;
}

extern "C" void kernel_launch(void* const* d_in, const int* in_sizes, int n_in,
                              void* d_out, int out_size, void* d_ws, size_t ws_size,
                              hipStream_t stream) {
    const int*   src     = (const int*)  d_in[0];
    const int*   dst     = (const int*)  d_in[1];
    const float* t       = (const float*)d_in[2];
    const float* x_pad   = (const float*)d_in[3];
    const float* t_pad   = (const float*)d_in[4];
    const float* emb_src = (const float*)d_in[5];
    const float* emb_dst = (const float*)d_in[6];
    const float* alpha_p = (const float*)d_in[7];
    const float* beta_p  = (const float*)d_in[8];
    float* out = (float*)d_out;

    const int blocks = NEVENTS / WAVES_PER_BLOCK;   // 4096 blocks x 256 threads
    markov_kernel<<<blocks, 64 * WAVES_PER_BLOCK, 0, stream>>>(
        src, dst, t, x_pad, t_pad, emb_src, emb_dst, alpha_p, beta_p, out);
}